// Round 5
// baseline (144.903 us; speedup 1.0000x reference)
//
#include <hip/hip_runtime.h>

// Problem constants (B,C,H,W)=(2,256,56,56), Cr=64, K=7, G=16, stride=1
#define HW     3136          // 56*56
#define C_IN   256
#define CR     64
#define KKG    784           // 49*16
#define NB     2             // batch
#define NPIX   6272          // NB*HW
#define NT25   25            // p-tiles of 256 over NPIX
#define BN_EPS 1e-5f

// Device-global scratch (fully rewritten every call; no cross-call state)
__device__ float g_T[CR * NPIX];           // conv1 output (pre-BN) [o][p]
__device__ float g_bs[2 * CR * NT25];      // per-block partial sum/sumsq [2][o][px]
__device__ float g_xg[16 * NPIX * 16];     // x transposed: [d][p][cg] = x[b][16cg+d][hw]
__device__ float g_w1t[C_IN * CR];         // w1T[c][o] = w1[o][c]   (256 x 64)
__device__ float g_w2t[CR * KKG];          // w2T[c][o] = w2[o][c]   (64 x 784)

// ---------------- k0: transpose w1 and w2 (tiny) ----------------
// grid (25), block 256, grid-stride over 16384 + 50176 elements.
__global__ __launch_bounds__(256) void k0_wt(const float* __restrict__ w1,
                                             const float* __restrict__ w2) {
  int idx = blockIdx.x * 256 + threadIdx.x;
  for (int i = idx; i < 16384 + 50176; i += 25 * 256) {
    if (i < 16384) {
      int c = i >> 6, o = i & 63;            // w1T[c*64+o] = w1[o*256+c]
      g_w1t[i] = w1[o * C_IN + c];
    } else {
      int j = i - 16384;
      int c = j / KKG, o = j - c * KKG;      // w2T[c*784+o] = w2[o*64+c]
      g_w2t[j] = w2[o * CR + c];
    }
  }
}

// ---------------- kA: fused conv1(full-K, o-tile 8)+stats | x-transpose ----------------
// grid (25, 24), block 256.
//   y in [0,8):  conv1 for o-range y*8..y*8+8 at p-tile x; write g_T + g_bs partials.
//   y in [8,24): transpose slice d=y-8 at p-tile x into g_xg.
__global__ __launch_bounds__(256) void kA(const float* __restrict__ x,
                                          const float* __restrict__ b1) {
  int xt = blockIdx.x;
  int p  = xt * 256 + threadIdx.x;
  int y  = blockIdx.y;
  if (y < 8) {
    int o0 = y * 8;
    bool valid = (p < NPIX);
    int b = (p >= HW) ? 1 : 0;
    int u = p - b * HW;
    const float* xb = x + (size_t)b * (C_IN * HW) + u;
    const float* wt = g_w1t + o0;            // w1T[c*64 + o]

    float acc[8];
#pragma unroll
    for (int i = 0; i < 8; ++i) acc[i] = b1[o0 + i];
    if (valid) {
#pragma unroll 8
      for (int c = 0; c < C_IN; ++c) {
        float xv = xb[(size_t)c * HW];       // coalesced across lanes
#pragma unroll
        for (int i = 0; i < 8; ++i)
          acc[i] += wt[c * CR + i] * xv;     // contiguous uniform -> s_load_dwordx8
      }
    }
    // store T + block-level stats partials (all threads reach the barrier)
    __shared__ float sdA[8][4], sdB[8][4];
    int lane = threadIdx.x & 63, wid = threadIdx.x >> 6;
#pragma unroll
    for (int i = 0; i < 8; ++i) {
      float v = valid ? acc[i] : 0.0f;
      if (valid) g_T[(size_t)(o0 + i) * NPIX + p] = v;
      float a = v, q = v * v;
#pragma unroll
      for (int off = 32; off > 0; off >>= 1) {
        a += __shfl_down(a, off);
        q += __shfl_down(q, off);
      }
      if (lane == 0) { sdA[i][wid] = a; sdB[i][wid] = q; }
    }
    __syncthreads();
    if (threadIdx.x < 8) {
      int i = threadIdx.x;
      float S  = sdA[i][0] + sdA[i][1] + sdA[i][2] + sdA[i][3];
      float S2 = sdB[i][0] + sdB[i][1] + sdB[i][2] + sdB[i][3];
      g_bs[(o0 + i) * NT25 + xt]             = S;
      g_bs[CR * NT25 + (o0 + i) * NT25 + xt] = S2;
    }
  } else {
    int d = y - 8;
    if (p >= NPIX) return;
    int b  = (p >= HW) ? 1 : 0;
    int hw = p - b * HW;
    const float* xp = x + ((size_t)(b * C_IN + d)) * HW + hw;
    float r[16];
#pragma unroll
    for (int cg = 0; cg < 16; ++cg)
      r[cg] = xp[(size_t)cg * (16 * HW)];
    float4* dst = (float4*)(g_xg + (((size_t)d * NPIX + p) << 4));
    dst[0] = make_float4(r[0], r[1], r[2], r[3]);
    dst[1] = make_float4(r[4], r[5], r[6], r[7]);
    dst[2] = make_float4(r[8], r[9], r[10], r[11]);
    dst[3] = make_float4(r[12], r[13], r[14], r[15]);
  }
}

// ---------------- kB: kout = w2 @ relu(BN(T)) + b2, BN finalized per-block ----------------
// grid (13, 49, 2), block 256. Each block: 16 output channels x 256 pixels.
__global__ __launch_bounds__(256) void kB_conv2(const float* __restrict__ gamma,
                                                const float* __restrict__ beta,
                                                const float* __restrict__ b2,
                                                float* __restrict__ kout) {
  __shared__ float ssc[CR], ssh[CR];
  if (threadIdx.x < CR) {
    int o = threadIdx.x;
    float S = 0.f, S2 = 0.f;
#pragma unroll
    for (int px = 0; px < NT25; ++px) {
      S  += g_bs[o * NT25 + px];
      S2 += g_bs[CR * NT25 + o * NT25 + px];
    }
    const float invN = 1.0f / (float)NPIX;
    float mean = S * invN;
    float var  = S2 * invN - mean * mean;   // population var matches jnp.var
    float inv  = rsqrtf(var + BN_EPS);
    float sc   = gamma[o] * inv;
    ssc[o] = sc;
    ssh[o] = beta[o] - mean * sc;
  }
  __syncthreads();

  int l  = blockIdx.x * 256 + threadIdx.x;
  if (l >= HW) return;
  int o0 = blockIdx.y * 16;
  int b  = blockIdx.z;

  float acc[16];
#pragma unroll
  for (int i = 0; i < 16; ++i) acc[i] = b2[o0 + i];

  const float* Tb = g_T + (size_t)b * HW + l;     // g_T[c*NPIX + b*HW + l]
  const float* wt = g_w2t + o0;                   // w2T[c*784 + o]
#pragma unroll 4
  for (int c = 0; c < CR; ++c) {
    float tv = Tb[(size_t)c * NPIX];
    tv = fmaxf(tv * ssc[c] + ssh[c], 0.0f);       // fused BN + ReLU (LDS broadcast)
#pragma unroll
    for (int i = 0; i < 16; ++i)
      acc[i] += wt[c * KKG + i] * tv;             // contiguous uniform -> s_load_dwordx16
  }
  float* kb = kout + (size_t)(b * KKG + o0) * HW + l;
#pragma unroll
  for (int i = 0; i < 16; ++i) kb[(size_t)i * HW] = acc[i];
}

// ---------------- K4: involution, s-per-block (uniform index math), float4 x-loads ----
// out[b][16cg+s][u] = sum_kk kout[b][16kk+s][u] * x_g[d][b*HW+pix][cg]
//   d=(16kk+s)/49, kk'=(16kk+s)%49, ki=kk'/7, kj=kk'%7,
//   pix=(u/56+ki-3)*56 + (u%56+kj-3), term dropped if OOB.
// grid (13, 16, 4), block 256: x=u-tile, y=s (uniform!), z=b*2+cg-half.
__global__ __launch_bounds__(256) void k4_invol(const float* __restrict__ kout,
                                                float* __restrict__ out) {
  int u = blockIdx.x * 256 + threadIdx.x;     // [0, 3136)
  if (u >= HW) return;
  int s   = blockIdx.y;                        // wave-uniform
  int bz  = blockIdx.z;
  int b   = bz >> 1;
  int cg0 = (bz & 1) * 8;

  int yrow = u / 56;
  int col  = u - yrow * 56;

  const float* kb = kout + (size_t)b * (KKG * HW) + (size_t)s * HW + u;
  const float* xg = g_xg + cg0;
  const size_t bHW16 = (size_t)(b * HW) << 4;

  float acc[8];
#pragma unroll
  for (int i = 0; i < 8; ++i) acc[i] = 0.0f;

#pragma unroll 7
  for (int kk = 0; kk < 49; ++kk) {
    int t16 = 16 * kk + s;          // scalar
    int d   = t16 / 49;             // scalar (SALU magic-mul)
    int kkp = t16 - d * 49;         // scalar
    int ki  = kkp / 7;              // scalar
    int kj  = kkp - ki * 7;         // scalar
    int yy = yrow + ki - 3, xx = col + kj - 3;
    float kv = kb[(size_t)kk * (16 * HW)];
    int off;
    if ((unsigned)yy < 56u && (unsigned)xx < 56u) {
      off = yy * 56 + xx;
    } else {
      off = 0;                      // safe address; kv=0 kills the term
      kv = 0.0f;
    }
    const float* xp = xg + (((size_t)d * NPIX + off) << 4) + bHW16;
    float4 xa  = *(const float4*)xp;
    float4 xb4 = *(const float4*)(xp + 4);
    acc[0] += kv * xa.x;  acc[1] += kv * xa.y;
    acc[2] += kv * xa.z;  acc[3] += kv * xa.w;
    acc[4] += kv * xb4.x; acc[5] += kv * xb4.y;
    acc[6] += kv * xb4.z; acc[7] += kv * xb4.w;
  }

  // out channel c = 16*(cg0+cg) + s
  float* ob = out + (size_t)b * (C_IN * HW) + ((size_t)(16 * cg0 + s)) * HW + u;
#pragma unroll
  for (int cg = 0; cg < 8; ++cg) ob[(size_t)cg * (16 * HW)] = acc[cg];
}

extern "C" void kernel_launch(void* const* d_in, const int* in_sizes, int n_in,
                              void* d_out, int out_size, void* d_ws, size_t ws_size,
                              hipStream_t stream) {
  const float* x     = (const float*)d_in[0];
  const float* w1    = (const float*)d_in[1];
  const float* b1    = (const float*)d_in[2];
  const float* gamma = (const float*)d_in[3];
  const float* beta  = (const float*)d_in[4];
  const float* w2    = (const float*)d_in[5];
  const float* b2    = (const float*)d_in[6];

  float* out  = (float*)d_out;                       // (B,256,56,56)
  float* kout = out + (size_t)NB * C_IN * HW;        // (B,784,56,56) raw == (B,49,56,56,16)

  k0_wt<<<dim3(25), 256, 0, stream>>>(w1, w2);
  kA<<<dim3(25, 24), 256, 0, stream>>>(x, b1);
  kB_conv2<<<dim3(13, 49, NB), 256, 0, stream>>>(gamma, beta, b2, kout);
  k4_invol<<<dim3(13, 16, 4), 256, 0, stream>>>(kout, out);
}